// Round 1
// baseline (28.039 us; speedup 1.0000x reference)
//
#include <hip/hip_runtime.h>

#define T_IN 2048
#define UPSCALE 480
#define T_OUT (T_IN * UPSCALE)   // 983040
#define BPB 64                    // blocks per batch
#define CHUNK (T_OUT / BPB)       // 15360 outputs per block
#define NTHREADS 256
#define ITERS (CHUNK / 4 / NTHREADS)  // 15 float4 groups per thread

__device__ __forceinline__ float signf(float x) {
    return (x > 0.f) ? 1.f : ((x < 0.f) ? -1.f : 0.f);
}

// Fritsch-Carlson edge slope (matches reference edge())
__device__ __forceinline__ float edge_slope(float dA, float dB) {
    float d = (3.f * dA - dB) * 0.5f;
    if (signf(d) != signf(dA)) {
        d = 0.f;
    } else if ((signf(dA) != signf(dB)) && (fabsf(d) > 3.f * fabsf(dA))) {
        d = 3.f * dA;
    }
    return d;
}

__global__ __launch_bounds__(NTHREADS) void pchip_upsample_kernel(
    const float* __restrict__ x, float* __restrict__ out)
{
    __shared__ float sy[T_IN];
    __shared__ float sd[T_IN];

    const int b   = blockIdx.y;
    const int cb  = blockIdx.x;
    const int tid = threadIdx.x;

    // Stage this batch's y row into LDS (8 KB)
    const float* xb = x + (size_t)b * T_IN;
    for (int i = tid; i < T_IN; i += NTHREADS) sy[i] = xb[i];
    __syncthreads();

    // Compute PCHIP slopes into LDS (redundant per block; trivial cost)
    for (int i = tid; i < T_IN; i += NTHREADS) {
        float dv;
        if (i == 0) {
            float dA = sy[1] - sy[0];
            float dB = sy[2] - sy[1];
            dv = edge_slope(dA, dB);
        } else if (i == T_IN - 1) {
            float dA = sy[T_IN - 1] - sy[T_IN - 2];
            float dB = sy[T_IN - 2] - sy[T_IN - 3];
            dv = edge_slope(dA, dB);
        } else {
            float d0 = sy[i] - sy[i - 1];
            float d1 = sy[i + 1] - sy[i];
            float prod = d0 * d1;
            // prod>0 implies d0+d1 != 0 (same sign), safe divide
            dv = (prod > 0.f) ? (2.f * prod / (d0 + d1)) : 0.f;
        }
        sd[i] = dv;
    }
    __syncthreads();

    const float STEP = (float)(T_IN - 1) / (float)(T_OUT - 1);

    float4* outv = (float4*)(out + (size_t)b * T_OUT + (size_t)cb * CHUNK);
    const int jbase = cb * CHUNK;

    for (int it = 0; it < ITERS; ++it) {
        const int g  = it * NTHREADS + tid;  // float4 group index within chunk
        const int j0 = jbase + g * 4;        // output index within batch
        float4 r;
        #pragma unroll
        for (int k = 0; k < 4; ++k) {
            float t = (float)(j0 + k) * STEP;
            int idx = (int)t;
            idx = idx > (T_IN - 2) ? (T_IN - 2) : idx;
            float s = t - (float)idx;

            float y0 = sy[idx],     y1 = sy[idx + 1];
            float d0 = sd[idx],     d1 = sd[idx + 1];

            float oms  = 1.f - s;
            float oms2 = oms * oms;
            float s2   = s * s;
            float h00  = (1.f + 2.f * s) * oms2;
            float h10  = s * oms2;
            float h01  = s2 * (3.f - 2.f * s);
            float h11  = s2 * (s - 1.f);

            float v = h00 * y0 + h10 * d0 + h01 * y1 + h11 * d1;
            if (k == 0) r.x = v;
            else if (k == 1) r.y = v;
            else if (k == 2) r.z = v;
            else r.w = v;
        }
        outv[g] = r;
    }
}

extern "C" void kernel_launch(void* const* d_in, const int* in_sizes, int n_in,
                              void* d_out, int out_size, void* d_ws, size_t ws_size,
                              hipStream_t stream) {
    (void)d_ws; (void)ws_size; (void)n_in; (void)out_size;
    const float* x = (const float*)d_in[0];
    float* out = (float*)d_out;
    const int B = in_sizes[0] / T_IN;  // 32

    dim3 grid(BPB, B);
    pchip_upsample_kernel<<<grid, NTHREADS, 0, stream>>>(x, out);
}